// Round 8
// baseline (957.670 us; speedup 1.0000x reference)
//
#include <hip/hip_runtime.h>

#define N_NODES   100000
#define N_EDGES   1200000
#define D         64
#define N_GRAPHS  128
#define N_CLASSES 3

#define TILE      64          // nodes per block in fused layer / scatter
#define LSTRIDE   68          // 64 + 4 pad (floats)

#define SCAN_CHUNK 512
#define SCAN_NB    ((N_NODES + SCAN_CHUNK - 1) / SCAN_CHUNK)   // 196 (<=256)

#define BSHIFT    4                                  // 16-node fill buckets
#define NB_FILL   ((N_NODES + 15) / 16)              // 6250

typedef unsigned int  uint;
typedef unsigned short ushort;

// ------------------------------------------------------------- bf16 helpers
__device__ __forceinline__ ushort bf16_rne(float f) {
    uint u = __float_as_uint(f);
    u += 0x7FFFu + ((u >> 16) & 1u);      // round to nearest even
    return (ushort)(u >> 16);
}
__device__ __forceinline__ void acc8(float* a, uint4 v) {
    a[0] += __uint_as_float(v.x << 16);
    a[1] += __uint_as_float(v.x & 0xFFFF0000u);
    a[2] += __uint_as_float(v.y << 16);
    a[3] += __uint_as_float(v.y & 0xFFFF0000u);
    a[4] += __uint_as_float(v.z << 16);
    a[5] += __uint_as_float(v.z & 0xFFFF0000u);
    a[6] += __uint_as_float(v.w << 16);
    a[7] += __uint_as_float(v.w & 0xFFFF0000u);
}

// ---------------------------------------------------------------- zero buffer
__global__ void zero_kernel(float* __restrict__ p, int n4) {
    int i = blockIdx.x * blockDim.x + threadIdx.x;
    if (i < n4) ((float4*)p)[i] = make_float4(0.f, 0.f, 0.f, 0.f);
}

// ------------------------------------------------------------ f32 -> bf16
__global__ __launch_bounds__(256) void cvt_bf16_kernel(
        const float* __restrict__ in, ushort* __restrict__ out, int n4) {
    int i = blockIdx.x * blockDim.x + threadIdx.x;
    if (i < n4) {
        float4 v = ((const float4*)in)[i];
        ushort4 o;
        o.x = bf16_rne(v.x); o.y = bf16_rne(v.y);
        o.z = bf16_rne(v.z); o.w = bf16_rne(v.w);
        ((ushort4*)out)[i] = o;
    }
}

// -------------------------------------------------------------- deg histogram
__global__ __launch_bounds__(256) void hist_kernel(
        const int* __restrict__ dst, int* __restrict__ deg) {
    int i = blockIdx.x * blockDim.x + threadIdx.x;
    int e = i * 4;
    if (e + 3 < N_EDGES) {
        int4 d = *(const int4*)(dst + e);
        atomicAdd(&deg[d.x], 1);
        atomicAdd(&deg[d.y], 1);
        atomicAdd(&deg[d.z], 1);
        atomicAdd(&deg[d.w], 1);
    } else {
        for (; e < N_EDGES; ++e) atomicAdd(&deg[dst[e]], 1);
    }
}

// ----------------------------------------------- scan phase 1: chunk partials
__global__ __launch_bounds__(256) void scan_partials_kernel(
        const int* __restrict__ deg, int* __restrict__ partial) {
    __shared__ int s[256];
    int b = blockIdx.x, t = threadIdx.x;
    int base = b * SCAN_CHUNK + t * 2;
    int v = 0;
    if (base     < N_NODES) v += deg[base];
    if (base + 1 < N_NODES) v += deg[base + 1];
    s[t] = v;
    __syncthreads();
    for (int d = 128; d > 0; d >>= 1) {
        if (t < d) s[t] += s[t + d];
        __syncthreads();
    }
    if (t == 0) partial[b] = s[0];
}

// ------------------------------------- scan phase 2: exclusive scan, 1 block
__global__ __launch_bounds__(256) void scan_mid_kernel(int* __restrict__ partial) {
    __shared__ int s[256];
    int t = threadIdx.x;
    int v = (t < SCAN_NB) ? partial[t] : 0;
    s[t] = v;
    __syncthreads();
    for (int d = 1; d < 256; d <<= 1) {
        int u = (t >= d) ? s[t - d] : 0;
        __syncthreads();
        s[t] += u;
        __syncthreads();
    }
    if (t < SCAN_NB) partial[t] = s[t] - v;   // exclusive
}

// --------------- scan phase 3: emit row_ptr + fill-bucket cursors (dst>>4)
__global__ __launch_bounds__(256) void scan_emit_kernel(
        const int* __restrict__ deg, const int* __restrict__ partial,
        int* __restrict__ row_ptr, int* __restrict__ bcursor) {
    __shared__ int s[256];
    int b = blockIdx.x, t = threadIdx.x;
    int base = b * SCAN_CHUNK + t * 2;
    int d0 = (base     < N_NODES) ? deg[base]     : 0;
    int d1 = (base + 1 < N_NODES) ? deg[base + 1] : 0;
    int local = d0 + d1;
    s[t] = local;
    __syncthreads();
    for (int d = 1; d < 256; d <<= 1) {
        int u = (t >= d) ? s[t - d] : 0;
        __syncthreads();
        s[t] += u;
        __syncthreads();
    }
    int off = partial[b] + s[t] - local;
    if (base < N_NODES) {
        row_ptr[base] = off;
        if ((base & 15) == 0) bcursor[base >> 4] = off;   // bucket region base
    }
    if (base + 1 < N_NODES) row_ptr[base + 1] = off + d0;
    if (b == 0 && t == 0) row_ptr[N_NODES] = N_EDGES;
}

// ---------------- phase A: bucket fill (sequential writes within bucket region)
// packed edge = src | (dst&63)<<20  (src < 2^17)
__global__ __launch_bounds__(256) void bucket_fill_kernel(
        const int* __restrict__ src, const int* __restrict__ dst,
        int* __restrict__ bcursor, int* __restrict__ bedges) {
    int i = blockIdx.x * blockDim.x + threadIdx.x;
    int e = i * 4;
    if (e + 3 < N_EDGES) {
        int4 d = *(const int4*)(dst + e);
        int4 s = *(const int4*)(src + e);
        int p0 = atomicAdd(&bcursor[d.x >> BSHIFT], 1); bedges[p0] = s.x | ((d.x & 63) << 20);
        int p1 = atomicAdd(&bcursor[d.y >> BSHIFT], 1); bedges[p1] = s.y | ((d.y & 63) << 20);
        int p2 = atomicAdd(&bcursor[d.z >> BSHIFT], 1); bedges[p2] = s.z | ((d.z & 63) << 20);
        int p3 = atomicAdd(&bcursor[d.w >> BSHIFT], 1); bedges[p3] = s.w | ((d.w & 63) << 20);
    } else {
        for (; e < N_EDGES; ++e) {
            int p = atomicAdd(&bcursor[dst[e] >> BSHIFT], 1);
            bedges[p] = src[e] | ((dst[e] & 63) << 20);
        }
    }
}

// -------- phase B: per-node scatter. Block = 64 nodes; LDS cursors from row_ptr.
__global__ __launch_bounds__(256) void scatter_kernel(
        const int* __restrict__ bedges, const int* __restrict__ row_ptr,
        int* __restrict__ csr) {
    __shared__ int lcur[TILE];
    int node0 = blockIdx.x * TILE;
    int tid   = threadIdx.x;
    if (tid < TILE) {
        int n = node0 + tid;
        lcur[tid] = (n < N_NODES) ? row_ptr[n] : 0;
    }
    __syncthreads();
    int rbeg = row_ptr[node0];
    int nend = node0 + TILE; if (nend > N_NODES) nend = N_NODES;
    int rend = row_ptr[nend];
    for (int e = rbeg + tid; e < rend; e += 256) {
        int p    = bedges[e];
        int ldst = (p >> 20) & 63;
        int pos  = atomicAdd(&lcur[ldst], 1);
        csr[pos] = p & 0xFFFFF;
    }
}

// --------------------------- fused layer: gather + agg@Wr + h@Ws + br, relu
// h stored bf16 (128 B rows); accumulation f32. Per-node CSR gather, no atomics.
// LDS = aggS only (~17.7 KB) -> 8 blocks/CU (32 waves, 100%); GEMM reads x
// straight from global (8 KB tile is L1-resident) and weights from L1.
template<int DO_POOL>
__global__ __launch_bounds__(256, 8) void fused_layer_kernel(
        const ushort* __restrict__ hin,
        const int* __restrict__ row_ptr,
        const int* __restrict__ csr,
        const float* __restrict__ Wr,
        const float* __restrict__ br,
        const float* __restrict__ Ws,
        ushort* __restrict__ hout,
        const int* __restrict__ batch,
        float* __restrict__ g) {
    __shared__ float aggS[TILE * LSTRIDE];   // 17.4 KB
    __shared__ int   bS[TILE];

    const int tid   = threadIdx.x;
    const int node0 = blockIdx.x * TILE;

    if (DO_POOL && tid < TILE) {
        int n = node0 + tid;
        bS[tid] = (n < N_NODES) ? batch[n] : -1;
    }

    // ---- gather: 2 rounds x 32 nodes; thread = (node-slot, 16B slice of 8 feats)
    const int fq8 = (tid & 7) * 8;
    for (int r = 0; r < 2; ++r) {
        int ln = r * 32 + (tid >> 3);
        int n  = node0 + ln;
        float acc[8] = {0.f, 0.f, 0.f, 0.f, 0.f, 0.f, 0.f, 0.f};
        if (n < N_NODES) {
            int beg = row_ptr[n];
            int end = row_ptr[n + 1];
            int j = beg;
            for (; j + 4 <= end; j += 4) {
                int s0 = csr[j + 0], s1 = csr[j + 1];
                int s2 = csr[j + 2], s3 = csr[j + 3];
                uint4 v0 = *(const uint4*)(hin + (size_t)s0 * D + fq8);
                uint4 v1 = *(const uint4*)(hin + (size_t)s1 * D + fq8);
                uint4 v2 = *(const uint4*)(hin + (size_t)s2 * D + fq8);
                uint4 v3 = *(const uint4*)(hin + (size_t)s3 * D + fq8);
                acc8(acc, v0); acc8(acc, v1); acc8(acc, v2); acc8(acc, v3);
            }
            for (; j < end; ++j) {
                uint4 v = *(const uint4*)(hin + (size_t)csr[j] * D + fq8);
                acc8(acc, v);
            }
        }
        *(float4*)&aggS[ln * LSTRIDE + fq8]     = make_float4(acc[0], acc[1], acc[2], acc[3]);
        *(float4*)&aggS[ln * LSTRIDE + fq8 + 4] = make_float4(acc[4], acc[5], acc[6], acc[7]);
    }
    __syncthreads();

    // ---- GEMM: thread = (node-quad q, feature-quad fq)
    // x read from global as packed bf16 pairs (L1-hit); agg via float2 LDS reads.
    const int q  = tid >> 4;
    const int fq = tid & 15;
    const int f4 = fq * 4;
    const int n0 = node0 + 4 * q;
    const float4* Wr4 = (const float4*)Wr;   // Wr4[k*16+fq]
    const float4* Ws4 = (const float4*)Ws;
    // rows beyond N_NODES read workspace garbage; results are discarded below.
    const uint* x0p = (const uint*)(hin + (size_t)(n0 + 0) * D);
    const uint* x1p = (const uint*)(hin + (size_t)(n0 + 1) * D);
    const uint* x2p = (const uint*)(hin + (size_t)(n0 + 2) * D);
    const uint* x3p = (const uint*)(hin + (size_t)(n0 + 3) * D);
    float4 bias = *(const float4*)(br + f4);
    float4 c0 = bias, c1 = bias, c2 = bias, c3 = bias;

#pragma unroll 4
    for (int kk = 0; kk < 32; ++kk) {
        const int k0 = 2 * kk;
        float4 wrA = Wr4[k0 * 16 + fq];
        float4 wrB = Wr4[(k0 + 1) * 16 + fq];
        float4 wsA = Ws4[k0 * 16 + fq];
        float4 wsB = Ws4[(k0 + 1) * 16 + fq];
        uint u0 = x0p[kk], u1 = x1p[kk], u2 = x2p[kk], u3 = x3p[kk];
        float2 a0 = *(const float2*)&aggS[(4 * q + 0) * LSTRIDE + k0];
        float2 a1 = *(const float2*)&aggS[(4 * q + 1) * LSTRIDE + k0];
        float2 a2 = *(const float2*)&aggS[(4 * q + 2) * LSTRIDE + k0];
        float2 a3 = *(const float2*)&aggS[(4 * q + 3) * LSTRIDE + k0];
        float x0A = __uint_as_float(u0 << 16), x0B = __uint_as_float(u0 & 0xFFFF0000u);
        float x1A = __uint_as_float(u1 << 16), x1B = __uint_as_float(u1 & 0xFFFF0000u);
        float x2A = __uint_as_float(u2 << 16), x2B = __uint_as_float(u2 & 0xFFFF0000u);
        float x3A = __uint_as_float(u3 << 16), x3B = __uint_as_float(u3 & 0xFFFF0000u);
        c0.x += a0.x * wrA.x + x0A * wsA.x;  c0.y += a0.x * wrA.y + x0A * wsA.y;
        c0.z += a0.x * wrA.z + x0A * wsA.z;  c0.w += a0.x * wrA.w + x0A * wsA.w;
        c0.x += a0.y * wrB.x + x0B * wsB.x;  c0.y += a0.y * wrB.y + x0B * wsB.y;
        c0.z += a0.y * wrB.z + x0B * wsB.z;  c0.w += a0.y * wrB.w + x0B * wsB.w;
        c1.x += a1.x * wrA.x + x1A * wsA.x;  c1.y += a1.x * wrA.y + x1A * wsA.y;
        c1.z += a1.x * wrA.z + x1A * wsA.z;  c1.w += a1.x * wrA.w + x1A * wsA.w;
        c1.x += a1.y * wrB.x + x1B * wsB.x;  c1.y += a1.y * wrB.y + x1B * wsB.y;
        c1.z += a1.y * wrB.z + x1B * wsB.z;  c1.w += a1.y * wrB.w + x1B * wsB.w;
        c2.x += a2.x * wrA.x + x2A * wsA.x;  c2.y += a2.x * wrA.y + x2A * wsA.y;
        c2.z += a2.x * wrA.z + x2A * wsA.z;  c2.w += a2.x * wrA.w + x2A * wsA.w;
        c2.x += a2.y * wrB.x + x2B * wsB.x;  c2.y += a2.y * wrB.y + x2B * wsB.y;
        c2.z += a2.y * wrB.z + x2B * wsB.z;  c2.w += a2.y * wrB.w + x2B * wsB.w;
        c3.x += a3.x * wrA.x + x3A * wsA.x;  c3.y += a3.x * wrA.y + x3A * wsA.y;
        c3.z += a3.x * wrA.z + x3A * wsA.z;  c3.w += a3.x * wrA.w + x3A * wsA.w;
        c3.x += a3.y * wrB.x + x3B * wsB.x;  c3.y += a3.y * wrB.y + x3B * wsB.y;
        c3.z += a3.y * wrB.z + x3B * wsB.z;  c3.w += a3.y * wrB.w + x3B * wsB.w;
    }

    float4 cc[4] = {c0, c1, c2, c3};

    if (!DO_POOL) {
#pragma unroll
        for (int i = 0; i < 4; ++i) {
            int n = node0 + 4 * q + i;
            if (n < N_NODES) {
                ushort4 o;
                o.x = bf16_rne(fmaxf(cc[i].x, 0.f));
                o.y = bf16_rne(fmaxf(cc[i].y, 0.f));
                o.z = bf16_rne(fmaxf(cc[i].z, 0.f));
                o.w = bf16_rne(fmaxf(cc[i].w, 0.f));
                *(ushort4*)(hout + (size_t)n * D + f4) = o;
            }
        }
    } else {
        __syncthreads();   // everyone done reading aggS
#pragma unroll
        for (int i = 0; i < 4; ++i) {
            float* a = &aggS[(4 * q + i) * LSTRIDE + f4];
            a[0] = fmaxf(cc[i].x, 0.f);
            a[1] = fmaxf(cc[i].y, 0.f);
            a[2] = fmaxf(cc[i].z, 0.f);
            a[3] = fmaxf(cc[i].w, 0.f);
        }
        __syncthreads();
        int f    = tid & 63;
        int part = tid >> 6;
        int ln0  = part * 16;
        int cur  = bS[ln0];
        float acc = 0.f;
        for (int ln = ln0; ln < ln0 + 16; ++ln) {
            int b = bS[ln];
            if (b < 0) break;
            if (b != cur) {
                atomicAdd(&g[cur * D + f], acc);
                acc = 0.f;
                cur = b;
            }
            acc += aggS[ln * LSTRIDE + f];
        }
        if (cur >= 0) atomicAdd(&g[cur * D + f], acc);
    }
}

// ------------------------------------------------------------------- MLP head
__global__ __launch_bounds__(64) void head_kernel(
        const float* __restrict__ g,
        const float* __restrict__ Wfc1, const float* __restrict__ bfc1,
        const float* __restrict__ Wfc2, const float* __restrict__ bfc2,
        float* __restrict__ out) {
    __shared__ float hS[D];
    __shared__ float lS[N_CLASSES];
    int gr = blockIdx.x;
    int f  = threadIdx.x;

    float acc = bfc1[f];
#pragma unroll
    for (int k = 0; k < D; ++k) acc += g[gr * D + k] * Wfc1[k * D + f];
    hS[f] = fmaxf(acc, 0.f);
    __syncthreads();

    if (f < N_CLASSES) {
        float a = bfc2[f];
#pragma unroll
        for (int k = 0; k < D; ++k) a += hS[k] * Wfc2[k * N_CLASSES + f];
        lS[f] = a;
    }
    __syncthreads();

    if (f == 0) {
        float m = fmaxf(lS[0], fmaxf(lS[1], lS[2]));
        float s = expf(lS[0] - m) + expf(lS[1] - m) + expf(lS[2] - m);
        float lse = m + logf(s);
        out[gr * 3 + 0] = lS[0] - lse;
        out[gr * 3 + 1] = lS[1] - lse;
        out[gr * 3 + 2] = lS[2] - lse;
    }
}

// ---------------------------------------------------------------------- launch
extern "C" void kernel_launch(void* const* d_in, const int* in_sizes, int n_in,
                              void* d_out, int out_size, void* d_ws, size_t ws_size,
                              hipStream_t stream) {
    const float* x     = (const float*)d_in[0];
    const int*   edge  = (const int*)d_in[1];
    const int*   batch = (const int*)d_in[2];
    const float* Wr1 = (const float*)d_in[3];
    const float* br1 = (const float*)d_in[4];
    const float* Ws1 = (const float*)d_in[5];
    const float* Wr2 = (const float*)d_in[6];
    const float* br2 = (const float*)d_in[7];
    const float* Ws2 = (const float*)d_in[8];
    const float* Wr3 = (const float*)d_in[9];
    const float* br3 = (const float*)d_in[10];
    const float* Ws3 = (const float*)d_in[11];
    const float* Wfc1 = (const float*)d_in[12];
    const float* bfc1 = (const float*)d_in[13];
    const float* Wfc2 = (const float*)d_in[14];
    const float* bfc2 = (const float*)d_in[15];

    const int* src = edge;
    const int* dst = edge + N_EDGES;

    // workspace layout (16 B aligned)
    ushort* Xb     = (ushort*)d_ws;                       // 6.4M bf16
    ushort* Ab     = Xb + (size_t)N_NODES * D;            // 6.4M bf16
    ushort* Bb     = Ab + (size_t)N_NODES * D;            // 6.4M bf16
    float*  g      = (float*)(Bb + (size_t)N_NODES * D);  // 8192 f
    int*   deg     = (int*)(g + (size_t)N_GRAPHS * D);    // 100,000 i
    int*   row_ptr = deg + N_NODES;                       // 100,001 i
    int*   bcursor = row_ptr + (N_NODES + 3);             // 6,250 i (keep align)
    int*   partial = bcursor + NB_FILL + 2;               // 256 i
    int*   bedges  = partial + 256;                       // 1.2M i
    int*   csr     = bedges + N_EDGES;                    // 1.2M i

    dim3 blk256(256);
    dim3 grdE4((N_EDGES / 4 + 255) / 256);
    dim3 grdT((N_NODES + TILE - 1) / TILE);
    const int nodeF4 = N_NODES * D / 4;

    // ---- zeros (deg; g)
    zero_kernel<<<dim3((N_NODES / 4 + 255) / 256), blk256, 0, stream>>>((float*)deg, N_NODES / 4);
    zero_kernel<<<dim3((N_GRAPHS * D / 4 + 255) / 256), blk256, 0, stream>>>(g, N_GRAPHS * D / 4);

    // ---- CSR build: deg -> row_ptr (+bucket cursors) -> bucket fill -> scatter
    hist_kernel<<<grdE4, blk256, 0, stream>>>(dst, deg);
    scan_partials_kernel<<<dim3(SCAN_NB), blk256, 0, stream>>>(deg, partial);
    scan_mid_kernel<<<dim3(1), blk256, 0, stream>>>(partial);
    scan_emit_kernel<<<dim3(SCAN_NB), blk256, 0, stream>>>(deg, partial, row_ptr, bcursor);
    bucket_fill_kernel<<<grdE4, blk256, 0, stream>>>(src, dst, bcursor, bedges);
    scatter_kernel<<<grdT, blk256, 0, stream>>>(bedges, row_ptr, csr);

    // ---- x -> bf16
    cvt_bf16_kernel<<<dim3((nodeF4 + 255) / 256), blk256, 0, stream>>>(x, Xb, nodeF4);

    // ---- 3 fused GraphConv layers (layer 3 pools directly into g)
    fused_layer_kernel<0><<<grdT, blk256, 0, stream>>>(Xb, row_ptr, csr, Wr1, br1, Ws1, Ab, batch, g);
    fused_layer_kernel<0><<<grdT, blk256, 0, stream>>>(Ab, row_ptr, csr, Wr2, br2, Ws2, Bb, batch, g);
    fused_layer_kernel<1><<<grdT, blk256, 0, stream>>>(Bb, row_ptr, csr, Wr3, br3, Ws3, Ab, batch, g);

    // ---- head
    head_kernel<<<dim3(N_GRAPHS), dim3(64), 0, stream>>>(g, Wfc1, bfc1, Wfc2, bfc2, (float*)d_out);
}

// Round 9
// 418.865 us; speedup vs baseline: 2.2863x; 2.2863x over previous
//
#include <hip/hip_runtime.h>

#define N_NODES   100000
#define N_EDGES   1200000
#define D         64
#define N_GRAPHS  128
#define N_CLASSES 3

#define TILE      64          // nodes per block in fused layer / scatter
#define LSTRIDE   68          // 64 + 4 pad (floats)

#define SCAN_CHUNK 512
#define SCAN_NB    ((N_NODES + SCAN_CHUNK - 1) / SCAN_CHUNK)   // 196 (<=256)

#define BSHIFT    4                                  // 16-node fill buckets
#define NB_FILL   ((N_NODES + 15) / 16)              // 6250

typedef unsigned int  uint;
typedef unsigned short ushort;

// ------------------------------------------------------------- bf16 helpers
__device__ __forceinline__ ushort bf16_rne(float f) {
    uint u = __float_as_uint(f);
    u += 0x7FFFu + ((u >> 16) & 1u);      // round to nearest even
    return (ushort)(u >> 16);
}
__device__ __forceinline__ void acc8(float* a, uint4 v) {
    a[0] += __uint_as_float(v.x << 16);
    a[1] += __uint_as_float(v.x & 0xFFFF0000u);
    a[2] += __uint_as_float(v.y << 16);
    a[3] += __uint_as_float(v.y & 0xFFFF0000u);
    a[4] += __uint_as_float(v.z << 16);
    a[5] += __uint_as_float(v.z & 0xFFFF0000u);
    a[6] += __uint_as_float(v.w << 16);
    a[7] += __uint_as_float(v.w & 0xFFFF0000u);
}

// ---------------------------------------------------------------- zero buffer
__global__ void zero_kernel(float* __restrict__ p, int n4) {
    int i = blockIdx.x * blockDim.x + threadIdx.x;
    if (i < n4) ((float4*)p)[i] = make_float4(0.f, 0.f, 0.f, 0.f);
}

// ------------------------------------------------------------ f32 -> bf16
__global__ __launch_bounds__(256) void cvt_bf16_kernel(
        const float* __restrict__ in, ushort* __restrict__ out, int n4) {
    int i = blockIdx.x * blockDim.x + threadIdx.x;
    if (i < n4) {
        float4 v = ((const float4*)in)[i];
        ushort4 o;
        o.x = bf16_rne(v.x); o.y = bf16_rne(v.y);
        o.z = bf16_rne(v.z); o.w = bf16_rne(v.w);
        ((ushort4*)out)[i] = o;
    }
}

// -------------------------------------------------------------- deg histogram
__global__ __launch_bounds__(256) void hist_kernel(
        const int* __restrict__ dst, int* __restrict__ deg) {
    int i = blockIdx.x * blockDim.x + threadIdx.x;
    int e = i * 4;
    if (e + 3 < N_EDGES) {
        int4 d = *(const int4*)(dst + e);
        atomicAdd(&deg[d.x], 1);
        atomicAdd(&deg[d.y], 1);
        atomicAdd(&deg[d.z], 1);
        atomicAdd(&deg[d.w], 1);
    } else {
        for (; e < N_EDGES; ++e) atomicAdd(&deg[dst[e]], 1);
    }
}

// ----------------------------------------------- scan phase 1: chunk partials
__global__ __launch_bounds__(256) void scan_partials_kernel(
        const int* __restrict__ deg, int* __restrict__ partial) {
    __shared__ int s[256];
    int b = blockIdx.x, t = threadIdx.x;
    int base = b * SCAN_CHUNK + t * 2;
    int v = 0;
    if (base     < N_NODES) v += deg[base];
    if (base + 1 < N_NODES) v += deg[base + 1];
    s[t] = v;
    __syncthreads();
    for (int d = 128; d > 0; d >>= 1) {
        if (t < d) s[t] += s[t + d];
        __syncthreads();
    }
    if (t == 0) partial[b] = s[0];
}

// ------------------------------------- scan phase 2: exclusive scan, 1 block
__global__ __launch_bounds__(256) void scan_mid_kernel(int* __restrict__ partial) {
    __shared__ int s[256];
    int t = threadIdx.x;
    int v = (t < SCAN_NB) ? partial[t] : 0;
    s[t] = v;
    __syncthreads();
    for (int d = 1; d < 256; d <<= 1) {
        int u = (t >= d) ? s[t - d] : 0;
        __syncthreads();
        s[t] += u;
        __syncthreads();
    }
    if (t < SCAN_NB) partial[t] = s[t] - v;   // exclusive
}

// --------------- scan phase 3: emit row_ptr + fill-bucket cursors (dst>>4)
__global__ __launch_bounds__(256) void scan_emit_kernel(
        const int* __restrict__ deg, const int* __restrict__ partial,
        int* __restrict__ row_ptr, int* __restrict__ bcursor) {
    __shared__ int s[256];
    int b = blockIdx.x, t = threadIdx.x;
    int base = b * SCAN_CHUNK + t * 2;
    int d0 = (base     < N_NODES) ? deg[base]     : 0;
    int d1 = (base + 1 < N_NODES) ? deg[base + 1] : 0;
    int local = d0 + d1;
    s[t] = local;
    __syncthreads();
    for (int d = 1; d < 256; d <<= 1) {
        int u = (t >= d) ? s[t - d] : 0;
        __syncthreads();
        s[t] += u;
        __syncthreads();
    }
    int off = partial[b] + s[t] - local;
    if (base < N_NODES) {
        row_ptr[base] = off;
        if ((base & 15) == 0) bcursor[base >> 4] = off;   // bucket region base
    }
    if (base + 1 < N_NODES) row_ptr[base + 1] = off + d0;
    if (b == 0 && t == 0) row_ptr[N_NODES] = N_EDGES;
}

// ---------------- phase A: bucket fill (sequential writes within bucket region)
// packed edge = src | (dst&63)<<20  (src < 2^17)
__global__ __launch_bounds__(256) void bucket_fill_kernel(
        const int* __restrict__ src, const int* __restrict__ dst,
        int* __restrict__ bcursor, int* __restrict__ bedges) {
    int i = blockIdx.x * blockDim.x + threadIdx.x;
    int e = i * 4;
    if (e + 3 < N_EDGES) {
        int4 d = *(const int4*)(dst + e);
        int4 s = *(const int4*)(src + e);
        int p0 = atomicAdd(&bcursor[d.x >> BSHIFT], 1); bedges[p0] = s.x | ((d.x & 63) << 20);
        int p1 = atomicAdd(&bcursor[d.y >> BSHIFT], 1); bedges[p1] = s.y | ((d.y & 63) << 20);
        int p2 = atomicAdd(&bcursor[d.z >> BSHIFT], 1); bedges[p2] = s.z | ((d.z & 63) << 20);
        int p3 = atomicAdd(&bcursor[d.w >> BSHIFT], 1); bedges[p3] = s.w | ((d.w & 63) << 20);
    } else {
        for (; e < N_EDGES; ++e) {
            int p = atomicAdd(&bcursor[dst[e] >> BSHIFT], 1);
            bedges[p] = src[e] | ((dst[e] & 63) << 20);
        }
    }
}

// -------- phase B: per-node scatter. Block = 64 nodes; LDS cursors from row_ptr.
__global__ __launch_bounds__(256) void scatter_kernel(
        const int* __restrict__ bedges, const int* __restrict__ row_ptr,
        int* __restrict__ csr) {
    __shared__ int lcur[TILE];
    int node0 = blockIdx.x * TILE;
    int tid   = threadIdx.x;
    if (tid < TILE) {
        int n = node0 + tid;
        lcur[tid] = (n < N_NODES) ? row_ptr[n] : 0;
    }
    __syncthreads();
    int rbeg = row_ptr[node0];
    int nend = node0 + TILE; if (nend > N_NODES) nend = N_NODES;
    int rend = row_ptr[nend];
    for (int e = rbeg + tid; e < rend; e += 256) {
        int p    = bedges[e];
        int ldst = (p >> 20) & 63;
        int pos  = atomicAdd(&lcur[ldst], 1);
        csr[pos] = p & 0xFFFFF;
    }
}

// --------------------------- fused layer: gather + agg@Wr + h@Ws + br, relu
// h stored bf16 (128 B rows); accumulation f32. Per-node CSR gather, no atomics.
// LDS = aggS only (~17.7 KB). launch_bounds(256,4): 128-VGPR cap -> NO SPILL
// (r8 lesson: (256,8)'s 64-reg cap spilled to scratch, 560 MB writes).
// Occupancy is then VGPR-limited (~6-8 blocks/CU at ~64-72 regs).
template<int DO_POOL>
__global__ __launch_bounds__(256, 4) void fused_layer_kernel(
        const ushort* __restrict__ hin,
        const int* __restrict__ row_ptr,
        const int* __restrict__ csr,
        const float* __restrict__ Wr,
        const float* __restrict__ br,
        const float* __restrict__ Ws,
        ushort* __restrict__ hout,
        const int* __restrict__ batch,
        float* __restrict__ g) {
    __shared__ float aggS[TILE * LSTRIDE];   // 17.4 KB
    __shared__ int   bS[TILE];

    const int tid   = threadIdx.x;
    const int node0 = blockIdx.x * TILE;

    if (DO_POOL && tid < TILE) {
        int n = node0 + tid;
        bS[tid] = (n < N_NODES) ? batch[n] : -1;
    }

    // ---- gather: 2 rounds x 32 nodes; thread = (node-slot, 16B slice of 8 feats)
    const int fq8 = (tid & 7) * 8;
    for (int r = 0; r < 2; ++r) {
        int ln = r * 32 + (tid >> 3);
        int n  = node0 + ln;
        float acc[8] = {0.f, 0.f, 0.f, 0.f, 0.f, 0.f, 0.f, 0.f};
        if (n < N_NODES) {
            int beg = row_ptr[n];
            int end = row_ptr[n + 1];
            int j = beg;
            for (; j + 4 <= end; j += 4) {
                int s0 = csr[j + 0], s1 = csr[j + 1];
                int s2 = csr[j + 2], s3 = csr[j + 3];
                uint4 v0 = *(const uint4*)(hin + (size_t)s0 * D + fq8);
                uint4 v1 = *(const uint4*)(hin + (size_t)s1 * D + fq8);
                uint4 v2 = *(const uint4*)(hin + (size_t)s2 * D + fq8);
                uint4 v3 = *(const uint4*)(hin + (size_t)s3 * D + fq8);
                acc8(acc, v0); acc8(acc, v1); acc8(acc, v2); acc8(acc, v3);
            }
            for (; j < end; ++j) {
                uint4 v = *(const uint4*)(hin + (size_t)csr[j] * D + fq8);
                acc8(acc, v);
            }
        }
        *(float4*)&aggS[ln * LSTRIDE + fq8]     = make_float4(acc[0], acc[1], acc[2], acc[3]);
        *(float4*)&aggS[ln * LSTRIDE + fq8 + 4] = make_float4(acc[4], acc[5], acc[6], acc[7]);
    }
    __syncthreads();

    // ---- GEMM: thread = (node-quad q, feature-quad fq)
    // x read from global as packed bf16 pairs (L1-hit); agg via float2 LDS reads.
    const int q  = tid >> 4;
    const int fq = tid & 15;
    const int f4 = fq * 4;
    const int n0 = node0 + 4 * q;
    const float4* Wr4 = (const float4*)Wr;   // Wr4[k*16+fq]
    const float4* Ws4 = (const float4*)Ws;
    // rows beyond N_NODES read workspace garbage; results are discarded below.
    const uint* x0p = (const uint*)(hin + (size_t)(n0 + 0) * D);
    const uint* x1p = (const uint*)(hin + (size_t)(n0 + 1) * D);
    const uint* x2p = (const uint*)(hin + (size_t)(n0 + 2) * D);
    const uint* x3p = (const uint*)(hin + (size_t)(n0 + 3) * D);
    float4 bias = *(const float4*)(br + f4);
    float4 c0 = bias, c1 = bias, c2 = bias, c3 = bias;

#pragma unroll 4
    for (int kk = 0; kk < 32; ++kk) {
        const int k0 = 2 * kk;
        float4 wrA = Wr4[k0 * 16 + fq];
        float4 wrB = Wr4[(k0 + 1) * 16 + fq];
        float4 wsA = Ws4[k0 * 16 + fq];
        float4 wsB = Ws4[(k0 + 1) * 16 + fq];
        uint u0 = x0p[kk], u1 = x1p[kk], u2 = x2p[kk], u3 = x3p[kk];
        float2 a0 = *(const float2*)&aggS[(4 * q + 0) * LSTRIDE + k0];
        float2 a1 = *(const float2*)&aggS[(4 * q + 1) * LSTRIDE + k0];
        float2 a2 = *(const float2*)&aggS[(4 * q + 2) * LSTRIDE + k0];
        float2 a3 = *(const float2*)&aggS[(4 * q + 3) * LSTRIDE + k0];
        float x0A = __uint_as_float(u0 << 16), x0B = __uint_as_float(u0 & 0xFFFF0000u);
        float x1A = __uint_as_float(u1 << 16), x1B = __uint_as_float(u1 & 0xFFFF0000u);
        float x2A = __uint_as_float(u2 << 16), x2B = __uint_as_float(u2 & 0xFFFF0000u);
        float x3A = __uint_as_float(u3 << 16), x3B = __uint_as_float(u3 & 0xFFFF0000u);
        c0.x += a0.x * wrA.x + x0A * wsA.x;  c0.y += a0.x * wrA.y + x0A * wsA.y;
        c0.z += a0.x * wrA.z + x0A * wsA.z;  c0.w += a0.x * wrA.w + x0A * wsA.w;
        c0.x += a0.y * wrB.x + x0B * wsB.x;  c0.y += a0.y * wrB.y + x0B * wsB.y;
        c0.z += a0.y * wrB.z + x0B * wsB.z;  c0.w += a0.y * wrB.w + x0B * wsB.w;
        c1.x += a1.x * wrA.x + x1A * wsA.x;  c1.y += a1.x * wrA.y + x1A * wsA.y;
        c1.z += a1.x * wrA.z + x1A * wsA.z;  c1.w += a1.x * wrA.w + x1A * wsA.w;
        c1.x += a1.y * wrB.x + x1B * wsB.x;  c1.y += a1.y * wrB.y + x1B * wsB.y;
        c1.z += a1.y * wrB.z + x1B * wsB.z;  c1.w += a1.y * wrB.w + x1B * wsB.w;
        c2.x += a2.x * wrA.x + x2A * wsA.x;  c2.y += a2.x * wrA.y + x2A * wsA.y;
        c2.z += a2.x * wrA.z + x2A * wsA.z;  c2.w += a2.x * wrA.w + x2A * wsA.w;
        c2.x += a2.y * wrB.x + x2B * wsB.x;  c2.y += a2.y * wrB.y + x2B * wsB.y;
        c2.z += a2.y * wrB.z + x2B * wsB.z;  c2.w += a2.y * wrB.w + x2B * wsB.w;
        c3.x += a3.x * wrA.x + x3A * wsA.x;  c3.y += a3.x * wrA.y + x3A * wsA.y;
        c3.z += a3.x * wrA.z + x3A * wsA.z;  c3.w += a3.x * wrA.w + x3A * wsA.w;
        c3.x += a3.y * wrB.x + x3B * wsB.x;  c3.y += a3.y * wrB.y + x3B * wsB.y;
        c3.z += a3.y * wrB.z + x3B * wsB.z;  c3.w += a3.y * wrB.w + x3B * wsB.w;
    }

    float4 cc[4] = {c0, c1, c2, c3};

    if (!DO_POOL) {
#pragma unroll
        for (int i = 0; i < 4; ++i) {
            int n = node0 + 4 * q + i;
            if (n < N_NODES) {
                ushort4 o;
                o.x = bf16_rne(fmaxf(cc[i].x, 0.f));
                o.y = bf16_rne(fmaxf(cc[i].y, 0.f));
                o.z = bf16_rne(fmaxf(cc[i].z, 0.f));
                o.w = bf16_rne(fmaxf(cc[i].w, 0.f));
                *(ushort4*)(hout + (size_t)n * D + f4) = o;
            }
        }
    } else {
        __syncthreads();   // everyone done reading aggS
#pragma unroll
        for (int i = 0; i < 4; ++i) {
            float* a = &aggS[(4 * q + i) * LSTRIDE + f4];
            a[0] = fmaxf(cc[i].x, 0.f);
            a[1] = fmaxf(cc[i].y, 0.f);
            a[2] = fmaxf(cc[i].z, 0.f);
            a[3] = fmaxf(cc[i].w, 0.f);
        }
        __syncthreads();
        int f    = tid & 63;
        int part = tid >> 6;
        int ln0  = part * 16;
        int cur  = bS[ln0];
        float acc = 0.f;
        for (int ln = ln0; ln < ln0 + 16; ++ln) {
            int b = bS[ln];
            if (b < 0) break;
            if (b != cur) {
                atomicAdd(&g[cur * D + f], acc);
                acc = 0.f;
                cur = b;
            }
            acc += aggS[ln * LSTRIDE + f];
        }
        if (cur >= 0) atomicAdd(&g[cur * D + f], acc);
    }
}

// ------------------------------------------------------------------- MLP head
__global__ __launch_bounds__(64) void head_kernel(
        const float* __restrict__ g,
        const float* __restrict__ Wfc1, const float* __restrict__ bfc1,
        const float* __restrict__ Wfc2, const float* __restrict__ bfc2,
        float* __restrict__ out) {
    __shared__ float hS[D];
    __shared__ float lS[N_CLASSES];
    int gr = blockIdx.x;
    int f  = threadIdx.x;

    float acc = bfc1[f];
#pragma unroll
    for (int k = 0; k < D; ++k) acc += g[gr * D + k] * Wfc1[k * D + f];
    hS[f] = fmaxf(acc, 0.f);
    __syncthreads();

    if (f < N_CLASSES) {
        float a = bfc2[f];
#pragma unroll
        for (int k = 0; k < D; ++k) a += hS[k] * Wfc2[k * N_CLASSES + f];
        lS[f] = a;
    }
    __syncthreads();

    if (f == 0) {
        float m = fmaxf(lS[0], fmaxf(lS[1], lS[2]));
        float s = expf(lS[0] - m) + expf(lS[1] - m) + expf(lS[2] - m);
        float lse = m + logf(s);
        out[gr * 3 + 0] = lS[0] - lse;
        out[gr * 3 + 1] = lS[1] - lse;
        out[gr * 3 + 2] = lS[2] - lse;
    }
}

// ---------------------------------------------------------------------- launch
extern "C" void kernel_launch(void* const* d_in, const int* in_sizes, int n_in,
                              void* d_out, int out_size, void* d_ws, size_t ws_size,
                              hipStream_t stream) {
    const float* x     = (const float*)d_in[0];
    const int*   edge  = (const int*)d_in[1];
    const int*   batch = (const int*)d_in[2];
    const float* Wr1 = (const float*)d_in[3];
    const float* br1 = (const float*)d_in[4];
    const float* Ws1 = (const float*)d_in[5];
    const float* Wr2 = (const float*)d_in[6];
    const float* br2 = (const float*)d_in[7];
    const float* Ws2 = (const float*)d_in[8];
    const float* Wr3 = (const float*)d_in[9];
    const float* br3 = (const float*)d_in[10];
    const float* Ws3 = (const float*)d_in[11];
    const float* Wfc1 = (const float*)d_in[12];
    const float* bfc1 = (const float*)d_in[13];
    const float* Wfc2 = (const float*)d_in[14];
    const float* bfc2 = (const float*)d_in[15];

    const int* src = edge;
    const int* dst = edge + N_EDGES;

    // workspace layout (16 B aligned)
    ushort* Xb     = (ushort*)d_ws;                       // 6.4M bf16
    ushort* Ab     = Xb + (size_t)N_NODES * D;            // 6.4M bf16
    ushort* Bb     = Ab + (size_t)N_NODES * D;            // 6.4M bf16
    float*  g      = (float*)(Bb + (size_t)N_NODES * D);  // 8192 f
    int*   deg     = (int*)(g + (size_t)N_GRAPHS * D);    // 100,000 i
    int*   row_ptr = deg + N_NODES;                       // 100,001 i
    int*   bcursor = row_ptr + (N_NODES + 3);             // 6,250 i (keep align)
    int*   partial = bcursor + NB_FILL + 2;               // 256 i
    int*   bedges  = partial + 256;                       // 1.2M i
    int*   csr     = bedges + N_EDGES;                    // 1.2M i

    dim3 blk256(256);
    dim3 grdE4((N_EDGES / 4 + 255) / 256);
    dim3 grdT((N_NODES + TILE - 1) / TILE);
    const int nodeF4 = N_NODES * D / 4;

    // ---- zeros (deg; g)
    zero_kernel<<<dim3((N_NODES / 4 + 255) / 256), blk256, 0, stream>>>((float*)deg, N_NODES / 4);
    zero_kernel<<<dim3((N_GRAPHS * D / 4 + 255) / 256), blk256, 0, stream>>>(g, N_GRAPHS * D / 4);

    // ---- CSR build: deg -> row_ptr (+bucket cursors) -> bucket fill -> scatter
    hist_kernel<<<grdE4, blk256, 0, stream>>>(dst, deg);
    scan_partials_kernel<<<dim3(SCAN_NB), blk256, 0, stream>>>(deg, partial);
    scan_mid_kernel<<<dim3(1), blk256, 0, stream>>>(partial);
    scan_emit_kernel<<<dim3(SCAN_NB), blk256, 0, stream>>>(deg, partial, row_ptr, bcursor);
    bucket_fill_kernel<<<grdE4, blk256, 0, stream>>>(src, dst, bcursor, bedges);
    scatter_kernel<<<grdT, blk256, 0, stream>>>(bedges, row_ptr, csr);

    // ---- x -> bf16
    cvt_bf16_kernel<<<dim3((nodeF4 + 255) / 256), blk256, 0, stream>>>(x, Xb, nodeF4);

    // ---- 3 fused GraphConv layers (layer 3 pools directly into g)
    fused_layer_kernel<0><<<grdT, blk256, 0, stream>>>(Xb, row_ptr, csr, Wr1, br1, Ws1, Ab, batch, g);
    fused_layer_kernel<0><<<grdT, blk256, 0, stream>>>(Ab, row_ptr, csr, Wr2, br2, Ws2, Bb, batch, g);
    fused_layer_kernel<1><<<grdT, blk256, 0, stream>>>(Bb, row_ptr, csr, Wr3, br3, Ws3, Ab, batch, g);

    // ---- head
    head_kernel<<<dim3(N_GRAPHS), dim3(64), 0, stream>>>(g, Wfc1, bfc1, Wfc2, bfc2, (float*)d_out);
}